// Round 2
// baseline (101.875 us; speedup 1.0000x reference)
//
#include <hip/hip_runtime.h>

// spatial_adaptive_operator: B=4, H=W=128, N=16384, C=128, P=4
// d_in: [0]=x (B,N,C) f32, [1]=deltaA (B,N,C) f32, [2]=H, [3]=W, [4]=Wo (8,C) f32, [5]=bo (8,) f32
// d_out: out (B,N,C) f32  ++  sampling_locations (B,N,1,1,P,2) f32

#define HW_ 128
#define CC_ 128
#define PP_ 4
#define NN_ (HW_ * HW_)

__global__ __launch_bounds__(256) void sao_kernel(
    const float* __restrict__ x,
    const float* __restrict__ dA,
    const float* __restrict__ Wo,
    const float* __restrict__ bo,
    float* __restrict__ out,
    float* __restrict__ locs)
{
    const int lane = threadIdx.x & 63;
    // wave id, forced scalar so all downstream index math lives in SGPRs
    const int wid = __builtin_amdgcn_readfirstlane(threadIdx.x >> 6) + blockIdx.x * 4;
    const int b = wid >> 14;             // wid / 16384
    const int n = wid & (NN_ - 1);
    const int ix = n & (HW_ - 1);
    const int iy = n >> 7;
    const size_t rowstart = (size_t)wid * CC_;   // == (b*NN + n)*CC

    const int vlane = 2 * lane;          // lane owns channels {2*lane, 2*lane+1}
    // prefetch deltaA pair early (independent of GEMV chain)
    const float2 d2 = *(const float2*)(dA + rowstart + vlane);

    // ---- GEMV: off[o] = dot(x_row, Wo[o]) + bo[o] ----
    // lane L: output o = L&7, channel chunk (L>>3)*16 .. +15  -> only 3 shfl levels
    const int o = lane & 7;
    const int chunk = lane >> 3;
    const float* xr = x + rowstart + chunk * 16;
    const float* wr = Wo + o * CC_ + chunk * 16;
    float partial = 0.0f;
#pragma unroll
    for (int j = 0; j < 4; ++j) {
        const float4 xv = *(const float4*)(xr + 4 * j);
        const float4 wv = *(const float4*)(wr + 4 * j);
        partial += xv.x * wv.x + xv.y * wv.y + xv.z * wv.z + xv.w * wv.w;
    }
#pragma unroll
    for (int m = 8; m <= 32; m <<= 1)
        partial += __shfl_xor(partial, m);
    const float offv = partial + bo[o];  // lane L holds off[L&7]

    const float refx = (ix + 0.5f) * (1.0f / HW_);
    const float refy = (iy + 0.5f) * (1.0f / HW_);

    // sampling_locations: 8 floats per point, lanes 0..7 hold off[0..7]
    if (lane < 8) {
        const float ref = (lane & 1) ? refy : refx;
        locs[(size_t)wid * 8 + lane] = ref + offv * (1.0f / HW_);
    }

    // broadcast the 8 offsets to SGPRs (lanes 0..7 hold them)
    float offs[8];
#pragma unroll
    for (int oo = 0; oo < 8; ++oo)
        offs[oo] = __int_as_float(__builtin_amdgcn_readlane(__float_as_int(offv), oo));

    float acc0 = 0.f, acc1 = 0.f;
#pragma unroll
    for (int p = 0; p < PP_; ++p) {
        // mirror reference arithmetic exactly (f32)
        const float locx = refx + offs[2 * p] * (1.0f / HW_);
        const float locy = refy + offs[2 * p + 1] * (1.0f / HW_);
        const float gx = 2.0f * locx - 1.0f;
        const float gy = 2.0f * locy - 1.0f;
        const float xp = ((gx + 1.0f) * (float)HW_ - 1.0f) * 0.5f;
        const float yp = ((gy + 1.0f) * (float)HW_ - 1.0f) * 0.5f;
        const float x0f = floorf(xp), y0f = floorf(yp);
        const float wx1 = xp - x0f, wy1 = yp - y0f;
        const float wx0 = 1.0f - wx1, wy0 = 1.0f - wy1;
        // uniform across lanes -> force SGPR so corner addressing is scalar
        const int ix0 = __builtin_amdgcn_readfirstlane((int)x0f);
        const int iy0 = __builtin_amdgcn_readfirstlane((int)y0f);

        float feat0 = 0.f, feat1 = 0.f, wt0 = 0.f, wt1 = 0.f;
#pragma unroll
        for (int k = 0; k < 4; ++k) {
            const int cx = ix0 + (k & 1);
            const int cy = iy0 + (k >> 1);
            const bool valid = (cx >= 0) & (cx < HW_) & (cy >= 0) & (cy < HW_);
            float w = ((k & 1) ? wx1 : wx0) * ((k >> 1) ? wy1 : wy0);
            w = valid ? w : 0.0f;
            const int cxc = min(max(cx, 0), HW_ - 1);
            const int cyc = min(max(cy, 0), HW_ - 1);
            // scalar base + per-lane 8B offset -> global_load_dwordx2 v, vlane, s[base]
            const size_t cb = ((size_t)b * NN_ + (size_t)(cyc * HW_ + cxc)) * CC_;
            const float2 xv = *(const float2*)(x + cb + vlane);
            const float2 dv = *(const float2*)(dA + cb + vlane);
            feat0 = fmaf(w, xv.x, feat0);
            feat1 = fmaf(w, xv.y, feat1);
            wt0 = fmaf(w, dv.x, wt0);
            wt1 = fmaf(w, dv.y, wt1);
        }
        acc0 = fmaf(feat0, wt0 - d2.x, acc0);
        acc1 = fmaf(feat1, wt1 - d2.y, acc1);
    }

    *(float2*)(out + rowstart + vlane) = make_float2(acc0 * 0.25f, acc1 * 0.25f);
}

extern "C" void kernel_launch(void* const* d_in, const int* in_sizes, int n_in,
                              void* d_out, int out_size, void* d_ws, size_t ws_size,
                              hipStream_t stream) {
    const float* x = (const float*)d_in[0];
    const float* dA = (const float*)d_in[1];
    const float* Wo = (const float*)d_in[4];
    const float* bo = (const float*)d_in[5];
    float* out = (float*)d_out;

    const int B = in_sizes[0] / (NN_ * CC_);            // 4
    float* locs = out + (size_t)B * NN_ * CC_;          // second tuple output

    const int waves = B * NN_;                           // one wave per point
    const int blocks = waves / 4;                        // 4 waves (256 thr) per block
    sao_kernel<<<blocks, 256, 0, stream>>>(x, dA, Wo, bo, out, locs);
}

// Round 4
// 73.432 us; speedup vs baseline: 1.3873x; 1.3873x over previous
//
#include <hip/hip_runtime.h>

// spatial_adaptive_operator: B=4, H=W=128, N=16384, C=128, P=4
// d_in: [0]=x (B,N,C) f32, [1]=deltaA (B,N,C) f32, [2]=H, [3]=W, [4]=Wo (8,C) f32, [5]=bo (8,) f32
// d_out: out (B,N,C) f32  ++  sampling_locations (B,N,1,1,P,2) f32
//
// R3 = R2 structure (2 points/wave, 4 ch/lane float4 gathers, XCD swizzle,
// non-temporal stores) with ext_vector_type for the nontemporal store.

#define HW_ 128
#define CC_ 128
#define PP_ 4
#define NN_ (HW_ * HW_)

typedef float f32x4 __attribute__((ext_vector_type(4)));

__global__ __launch_bounds__(256) void sao_kernel(
    const float* __restrict__ x,
    const float* __restrict__ dA,
    const float* __restrict__ Wo,
    const float* __restrict__ bo,
    float* __restrict__ out,
    float* __restrict__ locs)
{
    const int lane = threadIdx.x & 63;
    const int h = lane >> 5;           // half: which of the wave's 2 points
    const int s = lane & 31;           // sub-lane within the point
    const int wv = threadIdx.x >> 6;   // wave index in block (0..3)

    // bijective XCD-chunked swizzle: blocks with the same hw-XCD (orig%8) get
    // a contiguous work range -> each XCD's L2 sees a contiguous image band.
    const int nblk = gridDim.x;
    const int q = nblk >> 3, r = nblk & 7;
    const int xcd = blockIdx.x & 7;
    const int work = (xcd < r ? xcd * (q + 1) : r * (q + 1) + (xcd - r) * q)
                     + (blockIdx.x >> 3);

    const int pt = work * 8 + wv * 2 + h;   // point id in [0, B*N)
    const int b = pt >> 14;                 // pt / 16384
    const int n = pt & (NN_ - 1);
    const int ix = n & (HW_ - 1);
    const int iy = n >> 7;

    const size_t rowstart = (size_t)pt * CC_;

    // this lane's 4 channels of deltaA (prefetch early; independent of GEMV)
    const float4 d4 = *(const float4*)(dA + rowstart + s * 4);

    // ---- GEMV: off[o] = dot(x_row, Wo[o]) + bo[o], per half-wave ----
    // lane: output o = s&7 over channel chunk (s>>3)*32 .. +31 ; 2-level reduce
    const int o = s & 7;
    const int chunk = s >> 3;
    const float* xr = x + rowstart + chunk * 32;
    const float* wr = Wo + o * CC_ + chunk * 32;
    float partial = 0.0f;
#pragma unroll
    for (int j = 0; j < 8; ++j) {
        const float4 xv = *(const float4*)(xr + 4 * j);
        const float4 wvv = *(const float4*)(wr + 4 * j);
        partial += xv.x * wvv.x + xv.y * wvv.y + xv.z * wvv.z + xv.w * wvv.w;
    }
    partial += __shfl_xor(partial, 8);
    partial += __shfl_xor(partial, 16);
    const float offv = partial + bo[o];   // lanes s=0..7 hold off[0..7]

    const float refx = (ix + 0.5f) * (1.0f / HW_);
    const float refy = (iy + 0.5f) * (1.0f / HW_);

    // sampling_locations: 8 floats per point, layout (..., P, 2)
    if (s < 8) {
        const float ref = (s & 1) ? refy : refx;
        __builtin_nontemporal_store(ref + offv * (1.0f / HW_),
                                    locs + (size_t)pt * 8 + s);
    }

    // broadcast the 8 offsets within each half-wave
    float offs[8];
#pragma unroll
    for (int oo = 0; oo < 8; ++oo)
        offs[oo] = __shfl(offv, oo, 32);

    const size_t bbase = (size_t)b * (size_t)(NN_ * CC_) + s * 4;

    float4 acc = make_float4(0.f, 0.f, 0.f, 0.f);
#pragma unroll
    for (int p = 0; p < PP_; ++p) {
        // mirror reference arithmetic exactly (f32)
        const float locx = refx + offs[2 * p] * (1.0f / HW_);
        const float locy = refy + offs[2 * p + 1] * (1.0f / HW_);
        const float gx = 2.0f * locx - 1.0f;
        const float gy = 2.0f * locy - 1.0f;
        const float xp = ((gx + 1.0f) * (float)HW_ - 1.0f) * 0.5f;
        const float yp = ((gy + 1.0f) * (float)HW_ - 1.0f) * 0.5f;
        const float x0f = floorf(xp), y0f = floorf(yp);
        const float wx1 = xp - x0f, wy1 = yp - y0f;
        const float wx0 = 1.0f - wx1, wy0 = 1.0f - wy1;
        const int ix0 = (int)x0f, iy0 = (int)y0f;

        float4 feat = make_float4(0.f, 0.f, 0.f, 0.f);
        float4 wt = make_float4(0.f, 0.f, 0.f, 0.f);
#pragma unroll
        for (int k = 0; k < 4; ++k) {
            const int cx = ix0 + (k & 1);
            const int cy = iy0 + (k >> 1);
            const bool valid = (cx >= 0) & (cx < HW_) & (cy >= 0) & (cy < HW_);
            float w = ((k & 1) ? wx1 : wx0) * ((k >> 1) ? wy1 : wy0);
            w = valid ? w : 0.0f;
            const int pix = min(max(cy, 0), HW_ - 1) * HW_ + min(max(cx, 0), HW_ - 1);
            const size_t cb = bbase + (size_t)pix * CC_;
            const float4 xv = *(const float4*)(x + cb);
            const float4 dv = *(const float4*)(dA + cb);
            feat.x = fmaf(w, xv.x, feat.x);
            feat.y = fmaf(w, xv.y, feat.y);
            feat.z = fmaf(w, xv.z, feat.z);
            feat.w = fmaf(w, xv.w, feat.w);
            wt.x = fmaf(w, dv.x, wt.x);
            wt.y = fmaf(w, dv.y, wt.y);
            wt.z = fmaf(w, dv.z, wt.z);
            wt.w = fmaf(w, dv.w, wt.w);
        }
        acc.x = fmaf(feat.x, wt.x - d4.x, acc.x);
        acc.y = fmaf(feat.y, wt.y - d4.y, acc.y);
        acc.z = fmaf(feat.z, wt.z - d4.z, acc.z);
        acc.w = fmaf(feat.w, wt.w - d4.w, acc.w);
    }

    f32x4 res;
    res.x = acc.x * 0.25f;
    res.y = acc.y * 0.25f;
    res.z = acc.z * 0.25f;
    res.w = acc.w * 0.25f;
    __builtin_nontemporal_store(res, (f32x4*)(out + rowstart + s * 4));
}

extern "C" void kernel_launch(void* const* d_in, const int* in_sizes, int n_in,
                              void* d_out, int out_size, void* d_ws, size_t ws_size,
                              hipStream_t stream) {
    const float* x = (const float*)d_in[0];
    const float* dA = (const float*)d_in[1];
    const float* Wo = (const float*)d_in[4];
    const float* bo = (const float*)d_in[5];
    float* out = (float*)d_out;

    const int points = in_sizes[0] / CC_;               // B*N = 65536
    float* locs = out + (size_t)points * CC_;           // second tuple output

    const int blocks = points / 8;                      // 8 points per 256-thr block
    sao_kernel<<<blocks, 256, 0, stream>>>(x, dA, Wo, bo, out, locs);
}